// Round 6
// baseline (735.606 us; speedup 1.0000x reference)
//
#include <hip/hip_runtime.h>
#include <cstddef>
#include <cstdint>

// Bigram CE, row-major sweep: block = 16 seq rows x one column half; walks
// columns SEQUENTIALLY so logits writes are 16 long sequential DRAM streams
// per block. W pre-packed to fp16 MFMA fragments (single mfma_f32_16x16x32_f16
// per tile; fp16 err ~4e-3 << 0.24 threshold). Emb fragment is loop-invariant
// (4 VGPRs). Rowsum accumulates in registers across the whole sweep.
// N=4096 rows, V=100277, K=32.

using f32x4 = __attribute__((ext_vector_type(4))) float;
using f16x8 = __attribute__((ext_vector_type(8))) _Float16;

constexpr int N_ROWS = 4096;
constexpr int CHUNKS = 256;                 // 16-row chunks
constexpr int V_TILES = 6272;               // ceil(100277/16), padded cols 100352
constexpr int COLS_PER_STEP = 256;          // per block per step
constexpr int NSTEPS = 392;                 // 392*256 = 100352
constexpr int HALF_STEPS = NSTEPS / 2;      // 196
constexpr int WAVES = 8;                    // 512 threads
constexpr int TPW = 2;                      // tiles per wave per step

// d_ws layout (bytes)
constexpr size_t PART_OFF = 0;                        // part[2][4096] f32
constexpr size_t EF_OFF   = 64 * 1024;
constexpr size_t EF_BYTES = (size_t)CHUNKS * 64 * 16; // 256 KB
constexpr size_t WF_OFF   = EF_OFF + EF_BYTES;        // Wf: 6272*64*16B = 6.42 MB

static __device__ __forceinline__ uint4 pack8h(const float* f) {
    unsigned short u[8];
#pragma unroll
    for (int i = 0; i < 8; ++i) {
        _Float16 h = (_Float16)f[i];                  // v_cvt_f16_f32, RNE
        u[i] = __builtin_bit_cast(unsigned short, h);
    }
    uint4 r;
    r.x = (unsigned)u[0] | ((unsigned)u[1] << 16);
    r.y = (unsigned)u[2] | ((unsigned)u[3] << 16);
    r.z = (unsigned)u[4] | ((unsigned)u[5] << 16);
    r.w = (unsigned)u[6] | ((unsigned)u[7] << 16);
    return r;
}

// W -> fp16 fragments. Tile = col/16. Lane l: col = tile*16 + (l&15),
// k = (l>>4)*8 .. +7 contiguous (A-operand layout, W row-major [V][32]).
__global__ __launch_bounds__(256) void prep_wfrag(
    const float* __restrict__ W, uint4* __restrict__ Wf, int V)
{
    const int g    = blockIdx.x * 256 + threadIdx.x;   // V_TILES*64
    const int lane = g & 63;
    const int tile = g >> 6;
    int col = tile * 16 + (lane & 15);
    if (col >= V) col = V - 1;                         // clamped pad (masked later)
    const int k0 = (lane >> 4) * 8;
    const float* wp = W + (size_t)col * 32 + k0;
    float f[8];
    *reinterpret_cast<float4*>(f)     = *reinterpret_cast<const float4*>(wp);
    *reinterpret_cast<float4*>(f + 4) = *reinterpret_cast<const float4*>(wp + 4);
    Wf[g] = pack8h(f);
}

// emb[seq] -> fp16 fragments (B-operand). Lane l: n = l&15, k = (l>>4)*8..+7.
__global__ __launch_bounds__(256) void prep_efrag(
    const int* __restrict__ seq, const float* __restrict__ emb,
    uint4* __restrict__ Ef)
{
    const int g    = blockIdx.x * 256 + threadIdx.x;   // CHUNKS*64
    const int lane = g & 63;
    const int c    = g >> 6;
    const int row  = c * 16 + (lane & 15);
    const int k0   = (lane >> 4) * 8;
    const int idx  = seq[row];
    const float* ep = emb + (size_t)idx * 32 + k0;
    float f[8];
    *reinterpret_cast<float4*>(f)     = *reinterpret_cast<const float4*>(ep);
    *reinterpret_cast<float4*>(f + 4) = *reinterpret_cast<const float4*>(ep + 4);
    Ef[g] = pack8h(f);
}

__global__ __launch_bounds__(512) void bigram_main(
    const uint4* __restrict__ Wf,
    const float* __restrict__ bias,
    const uint4* __restrict__ Ef,
    float*       __restrict__ logits,
    float*       __restrict__ part,     // [2][4096]
    int V)
{
    __shared__ float lsum[WAVES][16];

    const int tid  = threadIdx.x;
    const int lane = tid & 63;
    const int wid  = tid >> 6;
    const int lgrp = lane >> 4;
    const int lcol = lane & 15;

    // XCD-aware decode (dispatch round-robins blocks over 8 XCDs): all blocks
    // on one XCD share the same W half -> 3.2 MB L2-resident working set.
    const int x     = blockIdx.x & 7;
    const int k     = blockIdx.x >> 3;        // 0..63
    const int half  = x & 1;
    const int chunk = (x >> 1) * 64 + k;      // bijective over 512 blocks

    const f16x8 E = __builtin_bit_cast(f16x8, Ef[chunk * 64 + lane]);  // invariant

    const int s0 = half * HALF_STEPS, s1 = s0 + HALF_STEPS;
    const int n  = chunk * 16 + lcol;
    float* rowp = logits + (size_t)n * V;
    const int cw = wid * (TPW * 16) + lgrp * 4;       // wave+lane col offset

    // Prefetch step s0 (never tail: s0*256+255 < V for both halves).
    uint4 Wc[TPW]; f32x4 Bc[TPW];
#pragma unroll
    for (int t = 0; t < TPW; ++t) {
        Wc[t] = Wf[(size_t)(s0 * 16 + wid * TPW + t) * 64 + lane];
        const float4 b4 = *reinterpret_cast<const float4*>(bias + s0 * COLS_PER_STEP + cw + t * 16);
        Bc[t] = f32x4{b4.x, b4.y, b4.z, b4.w};
    }

    float rs = 0.f;
    for (int s = s0; s < s1; ++s) {
        // ---- prefetch step s+1 (clamped; uniform tail check for bias OOB) ----
        const int sp = (s + 1 < s1) ? s + 1 : s;
        const bool nextFull = (sp * COLS_PER_STEP + COLS_PER_STEP) <= V;
        uint4 Wn[TPW]; f32x4 Bn[TPW];
#pragma unroll
        for (int t = 0; t < TPW; ++t) {
            Wn[t] = Wf[(size_t)(sp * 16 + wid * TPW + t) * 64 + lane];
            const int c0 = sp * COLS_PER_STEP + cw + t * 16;
            if (nextFull) {
                const float4 b4 = *reinterpret_cast<const float4*>(bias + c0);
                Bn[t] = f32x4{b4.x, b4.y, b4.z, b4.w};
            } else {
#pragma unroll
                for (int j = 0; j < 4; ++j) {
                    const int c = c0 + j;
                    Bn[t][j] = bias[c < V ? c : V - 1];
                }
            }
        }

        // ---- compute current step: 1 MFMA per tile, bias as C-init ----
        const bool full = (s * COLS_PER_STEP + COLS_PER_STEP) <= V;
        float se = 0.f;
#pragma unroll
        for (int t = 0; t < TPW; ++t) {
            f32x4 acc = __builtin_amdgcn_mfma_f32_16x16x32_f16(
                __builtin_bit_cast(f16x8, Wc[t]), E, Bc[t], 0, 0, 0);
            // D layout: row n = lane&15 (B-col), vocab col = c0 + (lane>>4)*4 + j.
            const int c0 = s * COLS_PER_STEP + cw + t * 16;
            if (full) {
                *reinterpret_cast<f32x4*>(rowp + c0) = acc;
                se += __expf(acc[0]) + __expf(acc[1]) +
                      __expf(acc[2]) + __expf(acc[3]);
            } else {
#pragma unroll
                for (int j = 0; j < 4; ++j) {
                    if (c0 + j < V) { rowp[c0 + j] = acc[j]; se += __expf(acc[j]); }
                }
            }
        }
        // Reduce over the 4 lanes sharing row n (lane ^16, ^32), accumulate.
        se += __shfl_xor(se, 16, 64);
        se += __shfl_xor(se, 32, 64);
        rs += se;

#pragma unroll
        for (int t = 0; t < TPW; ++t) { Wc[t] = Wn[t]; Bc[t] = Bn[t]; }
    }

    if (lane < 16) lsum[wid][lane] = rs;
    __syncthreads();
    if (tid < 16) {
        float s = 0.f;
#pragma unroll
        for (int w = 0; w < WAVES; ++w) s += lsum[w][tid];
        part[half * N_ROWS + chunk * 16 + tid] = s;
    }
}

// loss = mean( log(part0[n]+part1[n]) - (dot(emb[seq[n]], W[pred[n]]) + b[pred[n]]) )
__global__ void bigram_loss(
    const int*   __restrict__ seq,
    const int*   __restrict__ pred,
    const float* __restrict__ emb,
    const float* __restrict__ W,
    const float* __restrict__ bias,
    const float* __restrict__ part,
    float*       __restrict__ loss,
    int N)
{
    const int tid = threadIdx.x;
    float local = 0.f;
    for (int n = blockIdx.x * blockDim.x + tid; n < N; n += gridDim.x * blockDim.x) {
        const int r = seq[n], t = pred[n];
        const float4* e4 = reinterpret_cast<const float4*>(emb + (size_t)r * 32);
        const float4* w4 = reinterpret_cast<const float4*>(W + (size_t)t * 32);
        float d = bias[t];
#pragma unroll
        for (int i = 0; i < 8; ++i) {
            const float4 e = e4[i], w = w4[i];
            d += e.x * w.x + e.y * w.y + e.z * w.z + e.w * w.w;
        }
        local += __logf(part[n] + part[N_ROWS + n]) - d;
    }
#pragma unroll
    for (int off = 32; off >= 1; off >>= 1) local += __shfl_xor(local, off, 64);
    __shared__ float r4[4];
    if ((tid & 63) == 0) r4[tid >> 6] = local;
    __syncthreads();
    if (tid == 0) {
        const float s = r4[0] + r4[1] + r4[2] + r4[3];
        atomicAdd(loss, s / (float)N);
    }
}

extern "C" void kernel_launch(void* const* d_in, const int* in_sizes, int n_in,
                              void* d_out, int out_size, void* d_ws, size_t ws_size,
                              hipStream_t stream)
{
    const int*   seq  = (const int*)d_in[0];
    const int*   pred = (const int*)d_in[1];
    const float* emb  = (const float*)d_in[2];
    const float* W    = (const float*)d_in[3];
    const float* bias = (const float*)d_in[4];

    const int N = in_sizes[0];      // 4096
    const int V = in_sizes[4];      // 100277

    float* logits = (float*)d_out;
    float* loss   = logits + (size_t)N * V;

    char*  ws   = (char*)d_ws;
    float* part = (float*)(ws + PART_OFF);
    uint4* Ef   = (uint4*)(ws + EF_OFF);
    uint4* Wf   = (uint4*)(ws + WF_OFF);

    hipMemsetAsync((void*)loss, 0, sizeof(float), stream);

    hipLaunchKernelGGL(prep_wfrag, dim3(V_TILES * 64 / 256), dim3(256), 0, stream,
                       W, Wf, V);
    hipLaunchKernelGGL(prep_efrag, dim3(CHUNKS * 64 / 256), dim3(256), 0, stream,
                       seq, emb, Ef);

    hipLaunchKernelGGL(bigram_main, dim3(CHUNKS * 2), dim3(512), 0, stream,
                       Wf, bias, Ef, logits, part, V);

    hipLaunchKernelGGL(bigram_loss, dim3(16), dim3(256), 0, stream,
                       seq, pred, emb, W, bias, part, loss, N);
}

// Round 7
// 706.791 us; speedup vs baseline: 1.0408x; 1.0408x over previous
//
#include <hip/hip_runtime.h>
#include <cstddef>
#include <cstdint>

// Bigram CE via MFMA (fp16 fragments, 1 mfma/tile), column-block grid,
// wave-local LDS transpose -> 4x256B contiguous store segments per dwordx4,
// ZERO barriers in the main loop, no global atomics.
// N=4096 rows, V=100277, K=32.

using f32x4 = __attribute__((ext_vector_type(4))) float;
using f16x8 = __attribute__((ext_vector_type(8))) _Float16;

constexpr int N_ROWS = 4096;
constexpr int CHUNKS = 256;                    // 16-row chunks
constexpr int TILES  = 4;                      // 16-col tiles per wave
constexpr int WAVES_PB = 4;                    // 256 threads
constexpr int V_PER_BLOCK = WAVES_PB * TILES * 16;   // 256 cols
constexpr int NCOLB = (100277 + V_PER_BLOCK - 1) / V_PER_BLOCK;  // 392
constexpr int V_TILES = NCOLB * 16;            // 6272 (padded cols 100352)
constexpr int ROW_SPLITS = 4;
constexpr int CHUNKS_PER_SPLIT = CHUNKS / ROW_SPLITS;            // 64
constexpr int ROWS_PER_BLOCK = CHUNKS_PER_SPLIT * 16;            // 1024
constexpr int TSTR = 65;                       // LDS tile stride (floats)

// d_ws layout (bytes)
constexpr size_t RS_OFF = 0;                                  // rowsum 16KB
constexpr size_t EF_OFF = 64 * 1024;
constexpr size_t EF_BYTES = (size_t)CHUNKS * 64 * 16;         // 256 KB
constexpr size_t WF_OFF = EF_OFF + EF_BYTES;
constexpr size_t WF_BYTES = (size_t)V_TILES * 64 * 16;        // 6.42 MB
constexpr size_t PART_OFF = WF_OFF + WF_BYTES;                // NCOLB*4096 f32

static __device__ __forceinline__ uint4 pack8h(const float* f) {
    unsigned short u[8];
#pragma unroll
    for (int i = 0; i < 8; ++i) {
        _Float16 h = (_Float16)f[i];
        u[i] = __builtin_bit_cast(unsigned short, h);
    }
    uint4 r;
    r.x = (unsigned)u[0] | ((unsigned)u[1] << 16);
    r.y = (unsigned)u[2] | ((unsigned)u[3] << 16);
    r.z = (unsigned)u[4] | ((unsigned)u[5] << 16);
    r.w = (unsigned)u[6] | ((unsigned)u[7] << 16);
    return r;
}

// W -> fp16 A-operand fragments. Lane l: col = tile*16 + (l&15), k=(l>>4)*8..+7.
__global__ __launch_bounds__(256) void prep_wfrag(
    const float* __restrict__ W, uint4* __restrict__ Wf, int V)
{
    const int g    = blockIdx.x * 256 + threadIdx.x;   // V_TILES*64
    const int lane = g & 63;
    const int tile = g >> 6;
    int col = tile * 16 + (lane & 15);
    if (col >= V) col = V - 1;                         // pad clamp (masked later)
    const int k0 = (lane >> 4) * 8;
    const float* wp = W + (size_t)col * 32 + k0;
    float f[8];
    *reinterpret_cast<float4*>(f)     = *reinterpret_cast<const float4*>(wp);
    *reinterpret_cast<float4*>(f + 4) = *reinterpret_cast<const float4*>(wp + 4);
    Wf[g] = pack8h(f);
}

// emb[seq] -> fp16 B-operand fragments. Lane l: n = l&15, k = (l>>4)*8..+7.
__global__ __launch_bounds__(256) void prep_efrag(
    const int* __restrict__ seq, const float* __restrict__ emb,
    uint4* __restrict__ Ef)
{
    const int g    = blockIdx.x * 256 + threadIdx.x;   // CHUNKS*64
    const int lane = g & 63;
    const int c    = g >> 6;
    const int row  = c * 16 + (lane & 15);
    const int k0   = (lane >> 4) * 8;
    const int idx  = seq[row];
    const float* ep = emb + (size_t)idx * 32 + k0;
    float f[8];
    *reinterpret_cast<float4*>(f)     = *reinterpret_cast<const float4*>(ep);
    *reinterpret_cast<float4*>(f + 4) = *reinterpret_cast<const float4*>(ep + 4);
    Ef[g] = pack8h(f);
}

__global__ __launch_bounds__(256, 4) void bigram_main(
    const uint4* __restrict__ Wf,
    const float* __restrict__ bias,
    const uint4* __restrict__ Ef,
    float*       __restrict__ logits,
    float*       __restrict__ part,     // [NCOLB][4096]
    int V)
{
    __shared__ float tile[WAVES_PB][16 * TSTR];          // wave-private
    __shared__ float lsum[WAVES_PB][ROWS_PER_BLOCK];     // wave-private

    const int tid  = threadIdx.x;
    const int lane = tid & 63;
    const int wid  = tid >> 6;
    const int lgrp = lane >> 4;
    const int lcol = lane & 15;

    const int  colb = blockIdx.x >> 2;                   // 0..391
    const int  rsp  = blockIdx.x & 3;                    // 0..3
    const bool tail = (colb == NCOLB - 1);
    const int  cbase = colb * V_PER_BLOCK + wid * (TILES * 16);

    // W fragments + bias C-init: loaded ONCE (block-invariant).
    f16x8 Wfr[TILES];
    f32x4 binit[TILES];
#pragma unroll
    for (int t = 0; t < TILES; ++t) {
        Wfr[t] = __builtin_bit_cast(f16x8,
                   Wf[(size_t)(colb * 16 + wid * TILES + t) * 64 + lane]);
        const int c0 = cbase + t * 16 + lgrp * 4;        // acc j-cols base
        if (!tail) {
            const float4 b4 = *reinterpret_cast<const float4*>(bias + c0);
            binit[t] = f32x4{b4.x, b4.y, b4.z, b4.w};
        } else {
#pragma unroll
            for (int j = 0; j < 4; ++j) {
                const int c = c0 + j;
                binit[t][j] = bias[c < V ? c : V - 1];
            }
        }
    }

    float* tw  = &tile[wid][0];
    float* lsw = &lsum[wid][0];
    const int c_begin = rsp * CHUNKS_PER_SPLIT;

    uint4 Ecur = Ef[(size_t)c_begin * 64 + lane];

    for (int cc = 0; cc < CHUNKS_PER_SPLIT; ++cc) {
        const int c  = c_begin + cc;
        const int cn = (cc + 1 < CHUNKS_PER_SPLIT) ? c + 1 : c;
        const uint4 En = Ef[(size_t)cn * 64 + lane];     // prefetch

        const f16x8 E = __builtin_bit_cast(f16x8, Ecur);
        f32x4 acc[TILES];
#pragma unroll
        for (int t = 0; t < TILES; ++t)
            acc[t] = __builtin_amdgcn_mfma_f32_16x16x32_f16(Wfr[t], E, binit[t], 0, 0, 0);
        // D layout: seq row n = lane&15; vocab col = cbase + t*16 + (lane>>4)*4 + j.

        // exp row-partial (masked only in the single tail col-block)
        float s = 0.f;
        if (!tail) {
#pragma unroll
            for (int t = 0; t < TILES; ++t)
                s += __expf(acc[t][0]) + __expf(acc[t][1]) +
                     __expf(acc[t][2]) + __expf(acc[t][3]);
        } else {
#pragma unroll
            for (int t = 0; t < TILES; ++t)
#pragma unroll
                for (int j = 0; j < 4; ++j) {
                    const int col = cbase + t * 16 + lgrp * 4 + j;
                    if (col < V) s += __expf(acc[t][j]);
                }
        }
        s += __shfl_xor(s, 16, 64);
        s += __shfl_xor(s, 32, 64);
        if (lane < 16) lsw[cc * 16 + lcol] = s;          // row-partial, once

        // Wave-local LDS transpose: tile[n=lcol][col_local], stride 65.
#pragma unroll
        for (int t = 0; t < TILES; ++t)
#pragma unroll
            for (int j = 0; j < 4; ++j)
                tw[lcol * TSTR + (wid ? 0 : 0) + t * 16 + lgrp * 4 + j] = acc[t][j];

        // Read back row-major; each dwordx4 instr = 4 rows x 256B contiguous.
        const int colB = colb * V_PER_BLOCK + wid * 64 + lcol * 4;
#pragma unroll
        for (int r = 0; r < 4; ++r) {
            const int rl = r * 4 + lgrp;
            const float v0 = tw[rl * TSTR + lcol * 4 + 0];
            const float v1 = tw[rl * TSTR + lcol * 4 + 1];
            const float v2 = tw[rl * TSTR + lcol * 4 + 2];
            const float v3 = tw[rl * TSTR + lcol * 4 + 3];
            const int n = c * 16 + rl;
            float* dst = logits + (size_t)n * V + colB;
            if (!tail) {
                *reinterpret_cast<f32x4*>(dst) = f32x4{v0, v1, v2, v3};
            } else {
                if (colB     < V) dst[0] = v0;
                if (colB + 1 < V) dst[1] = v1;
                if (colB + 2 < V) dst[2] = v2;
                if (colB + 3 < V) dst[3] = v3;
            }
        }
        Ecur = En;
    }

    __syncthreads();   // the only barrier: combine 4 wave slices
    for (int r = tid; r < ROWS_PER_BLOCK; r += 256) {
        part[(size_t)colb * N_ROWS + rsp * ROWS_PER_BLOCK + r] =
            lsum[0][r] + lsum[1][r] + lsum[2][r] + lsum[3][r];
    }
}

// rowsum[n] = sum over column blocks of part[cb][n]
__global__ __launch_bounds__(256) void reduce_rowsum(
    const float* __restrict__ part,
    float*       __restrict__ rowsum,
    int nColBlocks, int N)
{
    const int n = blockIdx.x * 256 + threadIdx.x;
    if (n >= N) return;
    float s = 0.f;
#pragma unroll 4
    for (int p = 0; p < nColBlocks; ++p) s += part[(size_t)p * N + n];
    rowsum[n] = s;
}

// loss = mean( log(rowsum[n]) - (dot(emb[seq[n]], W[pred[n]]) + b[pred[n]]) )
__global__ void bigram_loss(
    const int*   __restrict__ seq,
    const int*   __restrict__ pred,
    const float* __restrict__ emb,
    const float* __restrict__ W,
    const float* __restrict__ bias,
    const float* __restrict__ rowsum,
    float*       __restrict__ loss,
    int N)
{
    const int tid = threadIdx.x;
    float local = 0.f;
    for (int n = blockIdx.x * blockDim.x + tid; n < N; n += gridDim.x * blockDim.x) {
        const int r = seq[n], t = pred[n];
        const float4* e4 = reinterpret_cast<const float4*>(emb + (size_t)r * 32);
        const float4* w4 = reinterpret_cast<const float4*>(W + (size_t)t * 32);
        float d = bias[t];
#pragma unroll
        for (int i = 0; i < 8; ++i) {
            const float4 e = e4[i], w = w4[i];
            d += e.x * w.x + e.y * w.y + e.z * w.z + e.w * w.w;
        }
        local += __logf(rowsum[n]) - d;
    }
#pragma unroll
    for (int off = 32; off >= 1; off >>= 1) local += __shfl_xor(local, off, 64);
    __shared__ float r4[4];
    if ((tid & 63) == 0) r4[tid >> 6] = local;
    __syncthreads();
    if (tid == 0) {
        const float s = r4[0] + r4[1] + r4[2] + r4[3];
        atomicAdd(loss, s / (float)N);
    }
}

extern "C" void kernel_launch(void* const* d_in, const int* in_sizes, int n_in,
                              void* d_out, int out_size, void* d_ws, size_t ws_size,
                              hipStream_t stream)
{
    const int*   seq  = (const int*)d_in[0];
    const int*   pred = (const int*)d_in[1];
    const float* emb  = (const float*)d_in[2];
    const float* W    = (const float*)d_in[3];
    const float* bias = (const float*)d_in[4];

    const int N = in_sizes[0];      // 4096
    const int V = in_sizes[4];      // 100277

    float* logits = (float*)d_out;
    float* loss   = logits + (size_t)N * V;

    char*  ws     = (char*)d_ws;
    float* rowsum = (float*)(ws + RS_OFF);
    uint4* Ef     = (uint4*)(ws + EF_OFF);
    uint4* Wf     = (uint4*)(ws + WF_OFF);
    float* part   = (float*)(ws + PART_OFF);

    hipMemsetAsync((void*)loss, 0, sizeof(float), stream);

    hipLaunchKernelGGL(prep_wfrag, dim3(V_TILES * 64 / 256), dim3(256), 0, stream,
                       W, Wf, V);
    hipLaunchKernelGGL(prep_efrag, dim3(CHUNKS * 64 / 256), dim3(256), 0, stream,
                       seq, emb, Ef);

    hipLaunchKernelGGL(bigram_main, dim3(NCOLB * ROW_SPLITS), dim3(256), 0, stream,
                       Wf, bias, Ef, logits, part, V);

    hipLaunchKernelGGL(reduce_rowsum, dim3((N + 255) / 256), dim3(256), 0, stream,
                       part, rowsum, NCOLB, N);

    hipLaunchKernelGGL(bigram_loss, dim3(16), dim3(256), 0, stream,
                       seq, pred, emb, W, bias, rowsum, loss, N);
}

// Round 8
// 620.855 us; speedup vs baseline: 1.1848x; 1.1384x over previous
//
#include <hip/hip_runtime.h>
#include <cstddef>
#include <cstdint>

// Bigram CE via MFMA (fp16 fragments, 1 mfma/tile). Round-4 structure
// (block-wide LDS transpose, 2 barriers/chunk) with 512-col blocks ->
// 2KB contiguous run per row per chunk (store-run-length is the measured
// lever for write BW). N=4096 rows, V=100277, K=32.

using f32x4 = __attribute__((ext_vector_type(4))) float;
using f16x8 = __attribute__((ext_vector_type(8))) _Float16;

constexpr int N_ROWS = 4096;
constexpr int CHUNKS = 256;                    // 16-row chunks
constexpr int TILES  = 8;                      // 16-col tiles per wave
constexpr int WAVES_PB = 4;                    // 256 threads
constexpr int V_PER_BLOCK = WAVES_PB * TILES * 16;               // 512 cols
constexpr int NCOLB = (100277 + V_PER_BLOCK - 1) / V_PER_BLOCK;  // 196
constexpr int V_TILES = NCOLB * (V_PER_BLOCK / 16);              // 6272
constexpr int ROW_SPLITS = 4;
constexpr int CHUNKS_PER_SPLIT = CHUNKS / ROW_SPLITS;            // 64
constexpr int TSTR = 516;                      // LDS tile stride (floats), 16B-aligned rows

// d_ws layout (bytes)
constexpr size_t RS_OFF = 0;                                  // rowsum 16KB
constexpr size_t EF_OFF = 64 * 1024;
constexpr size_t EF_BYTES = (size_t)CHUNKS * 64 * 16;         // 256 KB
constexpr size_t WF_OFF = EF_OFF + EF_BYTES;
constexpr size_t WF_BYTES = (size_t)V_TILES * 64 * 16;        // 6.42 MB
constexpr size_t PART_OFF = WF_OFF + WF_BYTES;                // NCOLB*4096 f32 = 3.2 MB

static __device__ __forceinline__ uint4 pack8h(const float* f) {
    unsigned short u[8];
#pragma unroll
    for (int i = 0; i < 8; ++i) {
        _Float16 h = (_Float16)f[i];
        u[i] = __builtin_bit_cast(unsigned short, h);
    }
    uint4 r;
    r.x = (unsigned)u[0] | ((unsigned)u[1] << 16);
    r.y = (unsigned)u[2] | ((unsigned)u[3] << 16);
    r.z = (unsigned)u[4] | ((unsigned)u[5] << 16);
    r.w = (unsigned)u[6] | ((unsigned)u[7] << 16);
    return r;
}

// W -> fp16 A-operand fragments. Lane l: col = tile*16 + (l&15), k=(l>>4)*8..+7.
__global__ __launch_bounds__(256) void prep_wfrag(
    const float* __restrict__ W, uint4* __restrict__ Wf, int V)
{
    const int g    = blockIdx.x * 256 + threadIdx.x;   // V_TILES*64
    const int lane = g & 63;
    const int tile = g >> 6;
    int col = tile * 16 + (lane & 15);
    if (col >= V) col = V - 1;                         // pad clamp (masked later)
    const int k0 = (lane >> 4) * 8;
    const float* wp = W + (size_t)col * 32 + k0;
    float f[8];
    *reinterpret_cast<float4*>(f)     = *reinterpret_cast<const float4*>(wp);
    *reinterpret_cast<float4*>(f + 4) = *reinterpret_cast<const float4*>(wp + 4);
    Wf[g] = pack8h(f);
}

// emb[seq] -> fp16 B-operand fragments. Lane l: n = l&15, k = (l>>4)*8..+7.
__global__ __launch_bounds__(256) void prep_efrag(
    const int* __restrict__ seq, const float* __restrict__ emb,
    uint4* __restrict__ Ef)
{
    const int g    = blockIdx.x * 256 + threadIdx.x;   // CHUNKS*64
    const int lane = g & 63;
    const int c    = g >> 6;
    const int row  = c * 16 + (lane & 15);
    const int k0   = (lane >> 4) * 8;
    const int idx  = seq[row];
    const float* ep = emb + (size_t)idx * 32 + k0;
    float f[8];
    *reinterpret_cast<float4*>(f)     = *reinterpret_cast<const float4*>(ep);
    *reinterpret_cast<float4*>(f + 4) = *reinterpret_cast<const float4*>(ep + 4);
    Ef[g] = pack8h(f);
}

__global__ __launch_bounds__(256) void bigram_main(
    const uint4* __restrict__ Wf,
    const float* __restrict__ bias,
    const uint4* __restrict__ Ef,
    float*       __restrict__ logits,
    float*       __restrict__ part,     // [NCOLB][4096]
    int V)
{
    __shared__ float tile[16][TSTR];     // 33 KB, block-wide
    __shared__ float lparts[WAVES_PB][16];

    const int tid  = threadIdx.x;
    const int lane = tid & 63;
    const int wid  = tid >> 6;
    const int lgrp = lane >> 4;
    const int lcol = lane & 15;

    const int  colb = blockIdx.x >> 2;                 // 0..195
    const int  rsp  = blockIdx.x & 3;                  // 0..3
    const bool tail = (colb == NCOLB - 1);
    const int  wloc  = wid * (TILES * 16);             // wave col offset in block
    const int  cbase = colb * V_PER_BLOCK + wloc;

    // W fragments + bias C-init: loaded ONCE (block-invariant).
    f16x8 Wfr[TILES];
    f32x4 binit[TILES];
#pragma unroll
    for (int t = 0; t < TILES; ++t) {
        Wfr[t] = __builtin_bit_cast(f16x8,
                   Wf[(size_t)(colb * (V_PER_BLOCK / 16) + wid * TILES + t) * 64 + lane]);
        const int c0 = cbase + t * 16 + lgrp * 4;      // acc j-cols base
        if (!tail) {
            const float4 b4 = *reinterpret_cast<const float4*>(bias + c0);
            binit[t] = f32x4{b4.x, b4.y, b4.z, b4.w};
        } else {
#pragma unroll
            for (int j = 0; j < 4; ++j) {
                const int c = c0 + j;
                binit[t][j] = bias[c < V ? c : V - 1];
            }
        }
    }

    const int c_begin = rsp * CHUNKS_PER_SPLIT;
    uint4 Ecur = Ef[(size_t)c_begin * 64 + lane];

    for (int cc = 0; cc < CHUNKS_PER_SPLIT; ++cc) {
        const int c  = c_begin + cc;
        const int cn = (cc + 1 < CHUNKS_PER_SPLIT) ? c + 1 : c;
        const uint4 En = Ef[(size_t)cn * 64 + lane];   // prefetch next chunk

        const f16x8 E = __builtin_bit_cast(f16x8, Ecur);
        f32x4 acc[TILES];
#pragma unroll
        for (int t = 0; t < TILES; ++t)
            acc[t] = __builtin_amdgcn_mfma_f32_16x16x32_f16(Wfr[t], E, binit[t], 0, 0, 0);
        // D layout: seq row n = lane&15; vocab col = cbase + t*16 + lgrp*4 + j.

        // exp row-partial
        float s = 0.f;
        if (!tail) {
#pragma unroll
            for (int t = 0; t < TILES; ++t)
                s += __expf(acc[t][0]) + __expf(acc[t][1]) +
                     __expf(acc[t][2]) + __expf(acc[t][3]);
        } else {
#pragma unroll
            for (int t = 0; t < TILES; ++t)
#pragma unroll
                for (int j = 0; j < 4; ++j) {
                    const int col = cbase + t * 16 + lgrp * 4 + j;
                    if (col < V) s += __expf(acc[t][j]);
                }
        }
        s += __shfl_xor(s, 16, 64);
        s += __shfl_xor(s, 32, 64);
        if (lane < 16) lparts[wid][lcol] = s;

        // Block-wide LDS transpose: tile[n=lcol][wloc + t*16 + lgrp*4 + j]
#pragma unroll
        for (int t = 0; t < TILES; ++t)
            *reinterpret_cast<f32x4*>(&tile[lcol][wloc + t * 16 + lgrp * 4]) = acc[t];

        __syncthreads();

        // part write (one 64B line per chunk)
        if (tid < 16)
            part[(size_t)colb * N_ROWS + c * 16 + tid] =
                lparts[0][tid] + lparts[1][tid] + lparts[2][tid] + lparts[3][tid];

        // Stores: wave w -> rows w*4..w*4+3; per row 2 back-to-back 1KB dwordx4
        // bursts = 2KB contiguous run per row.
#pragma unroll
        for (int r = 0; r < 4; ++r) {
            const int rl = wid * 4 + r;
            const int n  = c * 16 + rl;
            float* dst = logits + (size_t)n * V + colb * V_PER_BLOCK;
#pragma unroll
            for (int seg = 0; seg < 2; ++seg) {
                const int colL = seg * 256 + lane * 4;
                const f32x4 v = *reinterpret_cast<const f32x4*>(&tile[rl][colL]);
                if (!tail) {
                    *reinterpret_cast<f32x4*>(dst + colL) = v;
                } else {
                    const int colG = colb * V_PER_BLOCK + colL;
#pragma unroll
                    for (int j = 0; j < 4; ++j)
                        if (colG + j < V) dst[colL + j] = v[j];
                }
            }
        }
        __syncthreads();   // protect tile/lparts before next chunk
        Ecur = En;
    }
}

// rowsum[n] = sum over column blocks of part[cb][n]
__global__ __launch_bounds__(256) void reduce_rowsum(
    const float* __restrict__ part,
    float*       __restrict__ rowsum,
    int nColBlocks, int N)
{
    const int n = blockIdx.x * 256 + threadIdx.x;
    if (n >= N) return;
    float s = 0.f;
#pragma unroll 4
    for (int p = 0; p < nColBlocks; ++p) s += part[(size_t)p * N + n];
    rowsum[n] = s;
}

// loss = mean( log(rowsum[n]) - (dot(emb[seq[n]], W[pred[n]]) + b[pred[n]]) )
__global__ void bigram_loss(
    const int*   __restrict__ seq,
    const int*   __restrict__ pred,
    const float* __restrict__ emb,
    const float* __restrict__ W,
    const float* __restrict__ bias,
    const float* __restrict__ rowsum,
    float*       __restrict__ loss,
    int N)
{
    const int tid = threadIdx.x;
    float local = 0.f;
    for (int n = blockIdx.x * blockDim.x + tid; n < N; n += gridDim.x * blockDim.x) {
        const int r = seq[n], t = pred[n];
        const float4* e4 = reinterpret_cast<const float4*>(emb + (size_t)r * 32);
        const float4* w4 = reinterpret_cast<const float4*>(W + (size_t)t * 32);
        float d = bias[t];
#pragma unroll
        for (int i = 0; i < 8; ++i) {
            const float4 e = e4[i], w = w4[i];
            d += e.x * w.x + e.y * w.y + e.z * w.z + e.w * w.w;
        }
        local += __logf(rowsum[n]) - d;
    }
#pragma unroll
    for (int off = 32; off >= 1; off >>= 1) local += __shfl_xor(local, off, 64);
    __shared__ float r4[4];
    if ((tid & 63) == 0) r4[tid >> 6] = local;
    __syncthreads();
    if (tid == 0) {
        const float s = r4[0] + r4[1] + r4[2] + r4[3];
        atomicAdd(loss, s / (float)N);
    }
}

extern "C" void kernel_launch(void* const* d_in, const int* in_sizes, int n_in,
                              void* d_out, int out_size, void* d_ws, size_t ws_size,
                              hipStream_t stream)
{
    const int*   seq  = (const int*)d_in[0];
    const int*   pred = (const int*)d_in[1];
    const float* emb  = (const float*)d_in[2];
    const float* W    = (const float*)d_in[3];
    const float* bias = (const float*)d_in[4];

    const int N = in_sizes[0];      // 4096
    const int V = in_sizes[4];      // 100277

    float* logits = (float*)d_out;
    float* loss   = logits + (size_t)N * V;

    char*  ws     = (char*)d_ws;
    float* rowsum = (float*)(ws + RS_OFF);
    uint4* Ef     = (uint4*)(ws + EF_OFF);
    uint4* Wf     = (uint4*)(ws + WF_OFF);
    float* part   = (float*)(ws + PART_OFF);

    hipMemsetAsync((void*)loss, 0, sizeof(float), stream);

    hipLaunchKernelGGL(prep_wfrag, dim3(V_TILES * 64 / 256), dim3(256), 0, stream,
                       W, Wf, V);
    hipLaunchKernelGGL(prep_efrag, dim3(CHUNKS * 64 / 256), dim3(256), 0, stream,
                       seq, emb, Ef);

    hipLaunchKernelGGL(bigram_main, dim3(NCOLB * ROW_SPLITS), dim3(256), 0, stream,
                       Wf, bias, Ef, logits, part, V);

    hipLaunchKernelGGL(reduce_rowsum, dim3((N + 255) / 256), dim3(256), 0, stream,
                       part, rowsum, NCOLB, N);

    hipLaunchKernelGGL(bigram_loss, dim3(16), dim3(256), 0, stream,
                       seq, pred, emb, W, bias, rowsum, loss, N);
}

// Round 9
// 518.133 us; speedup vs baseline: 1.4197x; 1.1983x over previous
//
#include <hip/hip_runtime.h>
#include <cstddef>
#include <cstdint>

// Bigram CE via MFMA (fp16 fragments). Row-slab decomposition: block = 16
// consecutive rows, 1 block/CU (grid 256 x 1024 thr), sweeping 49 column
// windows of 2048. Per window: MFMA -> 128KB LDS tile -> each wave stores one
// row's 8KB contiguous run. Rowsum fully in-block. N=4096, V=100277, K=32.

using f32x4 = __attribute__((ext_vector_type(4))) float;
using f16x8 = __attribute__((ext_vector_type(8))) _Float16;

constexpr int N_ROWS  = 4096;
constexpr int ROWS_PB = 16;
constexpr int NBLK    = N_ROWS / ROWS_PB;      // 256 blocks = 1/CU
constexpr int WIN     = 2048;                  // cols per window
constexpr int NWIN    = 49;                    // 49*2048 = 100352 >= V
constexpr int TPB     = 1024;
constexpr int WAVES   = 16;
constexpr int V_TILES = NWIN * (WIN / 16);     // 6272
constexpr int TSTR    = 2052;                  // LDS row stride (floats), 16B-mult

// d_ws layout (bytes)
constexpr size_t RS_OFF = 0;                               // rowsum 16KB
constexpr size_t EF_OFF = 64 * 1024;
constexpr size_t EF_BYTES = (size_t)NBLK * 64 * 16;        // 256 KB
constexpr size_t WF_OFF = EF_OFF + EF_BYTES;               // 6.42 MB

static __device__ __forceinline__ uint4 pack8h(const float* f) {
    unsigned short u[8];
#pragma unroll
    for (int i = 0; i < 8; ++i) {
        _Float16 h = (_Float16)f[i];
        u[i] = __builtin_bit_cast(unsigned short, h);
    }
    uint4 r;
    r.x = (unsigned)u[0] | ((unsigned)u[1] << 16);
    r.y = (unsigned)u[2] | ((unsigned)u[3] << 16);
    r.z = (unsigned)u[4] | ((unsigned)u[5] << 16);
    r.w = (unsigned)u[6] | ((unsigned)u[7] << 16);
    return r;
}

// W -> fp16 A-operand fragments. Lane l: col = tile*16 + (l&15), k=(l>>4)*8..+7.
__global__ __launch_bounds__(256) void prep_wfrag(
    const float* __restrict__ W, uint4* __restrict__ Wf, int V)
{
    const int g    = blockIdx.x * 256 + threadIdx.x;   // V_TILES*64
    const int lane = g & 63;
    const int tile = g >> 6;
    int col = tile * 16 + (lane & 15);
    if (col >= V) col = V - 1;                         // pad clamp (masked later)
    const int k0 = (lane >> 4) * 8;
    const float* wp = W + (size_t)col * 32 + k0;
    float f[8];
    *reinterpret_cast<float4*>(f)     = *reinterpret_cast<const float4*>(wp);
    *reinterpret_cast<float4*>(f + 4) = *reinterpret_cast<const float4*>(wp + 4);
    Wf[g] = pack8h(f);
}

// emb[seq] -> fp16 B-operand fragments. Lane l: n = l&15, k = (l>>4)*8..+7.
__global__ __launch_bounds__(256) void prep_efrag(
    const int* __restrict__ seq, const float* __restrict__ emb,
    uint4* __restrict__ Ef)
{
    const int g    = blockIdx.x * 256 + threadIdx.x;   // NBLK*64
    const int lane = g & 63;
    const int c    = g >> 6;
    const int row  = c * 16 + (lane & 15);
    const int k0   = (lane >> 4) * 8;
    const int idx  = seq[row];
    const float* ep = emb + (size_t)idx * 32 + k0;
    float f[8];
    *reinterpret_cast<float4*>(f)     = *reinterpret_cast<const float4*>(ep);
    *reinterpret_cast<float4*>(f + 4) = *reinterpret_cast<const float4*>(ep + 4);
    Ef[g] = pack8h(f);
}

__global__ __launch_bounds__(TPB) void bigram_main(
    const uint4* __restrict__ Wf,
    const float* __restrict__ bias,
    const uint4* __restrict__ Ef,
    float*       __restrict__ logits,
    float*       __restrict__ rowsum,
    int V)
{
    __shared__ float buf[ROWS_PB][TSTR];     // 128.25 KB
    __shared__ float lsum[WAVES][ROWS_PB];   // 1 KB

    const int tid  = threadIdx.x;
    const int lane = tid & 63;
    const int wid  = tid >> 6;
    const int lgrp = lane >> 4;
    const int lcol = lane & 15;
    const int b    = blockIdx.x;

    // emb fragments for this block's 16 rows: loop-invariant.
    const f16x8 E = __builtin_bit_cast(f16x8, Ef[(size_t)b * 64 + lane]);
    const int wcol = wid * 128;                // wave's col offset inside window
    float rs = 0.f;

    for (int s = 0; s < NWIN; ++s) {
        const int  cbase = s * WIN;
        const bool last  = (s == NWIN - 1);

        // Load this window's 8 W fragments (8 independent loads in flight).
        uint4 Wc[8];
#pragma unroll
        for (int t = 0; t < 8; ++t)
            Wc[t] = Wf[(size_t)(s * (WIN / 16) + wid * 8 + t) * 64 + lane];

#pragma unroll
        for (int t = 0; t < 8; ++t) {
            const f32x4 z = {0.f, 0.f, 0.f, 0.f};
            f32x4 acc = __builtin_amdgcn_mfma_f32_16x16x32_f16(
                __builtin_bit_cast(f16x8, Wc[t]), E, z, 0, 0, 0);
            // D: seq row = lane&15; vocab col = cbase + wcol + t*16 + lgrp*4 + j.
            const int c0 = cbase + wcol + t * 16 + lgrp * 4;
            f32x4 x;
            if (!last) {
                const float4 b4 = *reinterpret_cast<const float4*>(bias + c0);
                x = acc + f32x4{b4.x, b4.y, b4.z, b4.w};
                rs += __expf(x[0]) + __expf(x[1]) + __expf(x[2]) + __expf(x[3]);
            } else {
#pragma unroll
                for (int j = 0; j < 4; ++j) {
                    const int c = c0 + j;
                    x[j] = acc[j] + bias[c < V ? c : V - 1];
                    if (c < V) rs += __expf(x[j]);
                }
            }
            *reinterpret_cast<f32x4*>(&buf[lcol][wcol + t * 16 + lgrp * 4]) = x;
        }
        __syncthreads();

        // Store phase: wave w stores row w's 8KB window as 8 back-to-back
        // 1KB dwordx4 bursts (ascending addresses).
        {
            const int n = b * ROWS_PB + wid;
            float* dst = logits + (size_t)n * V + cbase;
#pragma unroll
            for (int i = 0; i < 8; ++i) {
                const int colL = i * 256 + lane * 4;
                const f32x4 v = *reinterpret_cast<const f32x4*>(&buf[wid][colL]);
                if (!last) {
                    *reinterpret_cast<f32x4*>(dst + colL) = v;
                } else {
                    const int cg = cbase + colL;
                    if (cg + 3 < V) {
                        *reinterpret_cast<f32x4*>(dst + colL) = v;
                    } else {
#pragma unroll
                        for (int j = 0; j < 4; ++j)
                            if (cg + j < V) dst[colL + j] = v[j];
                    }
                }
            }
        }
        __syncthreads();   // protect buf before next window overwrites
    }

    // In-block rowsum: reduce over lgrp lanes, then over the 16 waves.
    rs += __shfl_xor(rs, 16, 64);
    rs += __shfl_xor(rs, 32, 64);
    if (lane < 16) lsum[wid][lane] = rs;
    __syncthreads();
    if (tid < ROWS_PB) {
        float t = 0.f;
#pragma unroll
        for (int w = 0; w < WAVES; ++w) t += lsum[w][tid];
        rowsum[b * ROWS_PB + tid] = t;
    }
}

// loss = mean( log(rowsum[n]) - (dot(emb[seq[n]], W[pred[n]]) + b[pred[n]]) )
__global__ void bigram_loss(
    const int*   __restrict__ seq,
    const int*   __restrict__ pred,
    const float* __restrict__ emb,
    const float* __restrict__ W,
    const float* __restrict__ bias,
    const float* __restrict__ rowsum,
    float*       __restrict__ loss,
    int N)
{
    const int tid = threadIdx.x;
    float local = 0.f;
    for (int n = blockIdx.x * blockDim.x + tid; n < N; n += gridDim.x * blockDim.x) {
        const int r = seq[n], t = pred[n];
        const float4* e4 = reinterpret_cast<const float4*>(emb + (size_t)r * 32);
        const float4* w4 = reinterpret_cast<const float4*>(W + (size_t)t * 32);
        float d = bias[t];
#pragma unroll
        for (int i = 0; i < 8; ++i) {
            const float4 e = e4[i], w = w4[i];
            d += e.x * w.x + e.y * w.y + e.z * w.z + e.w * w.w;
        }
        local += __logf(rowsum[n]) - d;
    }
#pragma unroll
    for (int off = 32; off >= 1; off >>= 1) local += __shfl_xor(local, off, 64);
    __shared__ float r4[4];
    if ((tid & 63) == 0) r4[tid >> 6] = local;
    __syncthreads();
    if (tid == 0) {
        const float s = r4[0] + r4[1] + r4[2] + r4[3];
        atomicAdd(loss, s / (float)N);
    }
}

extern "C" void kernel_launch(void* const* d_in, const int* in_sizes, int n_in,
                              void* d_out, int out_size, void* d_ws, size_t ws_size,
                              hipStream_t stream)
{
    const int*   seq  = (const int*)d_in[0];
    const int*   pred = (const int*)d_in[1];
    const float* emb  = (const float*)d_in[2];
    const float* W    = (const float*)d_in[3];
    const float* bias = (const float*)d_in[4];

    const int N = in_sizes[0];      // 4096
    const int V = in_sizes[4];      // 100277

    float* logits = (float*)d_out;
    float* loss   = logits + (size_t)N * V;

    char*  ws     = (char*)d_ws;
    float* rowsum = (float*)(ws + RS_OFF);
    uint4* Ef     = (uint4*)(ws + EF_OFF);
    uint4* Wf     = (uint4*)(ws + WF_OFF);

    hipMemsetAsync((void*)loss, 0, sizeof(float), stream);

    hipLaunchKernelGGL(prep_wfrag, dim3(V_TILES * 64 / 256), dim3(256), 0, stream,
                       W, Wf, V);
    hipLaunchKernelGGL(prep_efrag, dim3(NBLK * 64 / 256), dim3(256), 0, stream,
                       seq, emb, Ef);

    hipLaunchKernelGGL(bigram_main, dim3(NBLK), dim3(TPB), 0, stream,
                       Wf, bias, Ef, logits, rowsum, V);

    hipLaunchKernelGGL(bigram_loss, dim3(16), dim3(256), 0, stream,
                       seq, pred, emb, W, bias, rowsum, loss, N);
}

// Round 10
// 423.922 us; speedup vs baseline: 1.7352x; 1.2222x over previous
//
#include <hip/hip_runtime.h>
#include <cstddef>
#include <cstdint>

// Bigram CE via MFMA (fp16 fragments). Row-slab: block = 16 consecutive rows,
// 1 block/CU (grid 256 x 1024 thr), 49 column windows of 2048. Per window:
// MFMA -> 128KB LDS tile -> each wave stores one row's 8KB run with
// NON-TEMPORAL full-line stores (bypass L2 so Wf stays L2-resident).
// W fragments double-buffered in registers across windows.
// N=4096, V=100277, K=32.

using f32x4 = __attribute__((ext_vector_type(4))) float;
using f16x8 = __attribute__((ext_vector_type(8))) _Float16;

constexpr int N_ROWS  = 4096;
constexpr int ROWS_PB = 16;
constexpr int NBLK    = N_ROWS / ROWS_PB;      // 256 blocks = 1/CU
constexpr int WIN     = 2048;                  // cols per window
constexpr int NWIN    = 49;                    // 49*2048 = 100352 >= V
constexpr int TPB     = 1024;
constexpr int WAVES   = 16;
constexpr int V_TILES = NWIN * (WIN / 16);     // 6272
constexpr int TSTR    = 2052;                  // LDS row stride (floats), 16B-mult

// d_ws layout (bytes)
constexpr size_t RS_OFF = 0;                               // rowsum 16KB
constexpr size_t EF_OFF = 64 * 1024;
constexpr size_t EF_BYTES = (size_t)NBLK * 64 * 16;        // 256 KB
constexpr size_t WF_OFF = EF_OFF + EF_BYTES;               // 6.42 MB

static __device__ __forceinline__ uint4 pack8h(const float* f) {
    unsigned short u[8];
#pragma unroll
    for (int i = 0; i < 8; ++i) {
        _Float16 h = (_Float16)f[i];
        u[i] = __builtin_bit_cast(unsigned short, h);
    }
    uint4 r;
    r.x = (unsigned)u[0] | ((unsigned)u[1] << 16);
    r.y = (unsigned)u[2] | ((unsigned)u[3] << 16);
    r.z = (unsigned)u[4] | ((unsigned)u[5] << 16);
    r.w = (unsigned)u[6] | ((unsigned)u[7] << 16);
    return r;
}

// W -> fp16 A-operand fragments. Lane l: col = tile*16 + (l&15), k=(l>>4)*8..+7.
__global__ __launch_bounds__(256) void prep_wfrag(
    const float* __restrict__ W, uint4* __restrict__ Wf, int V)
{
    const int g    = blockIdx.x * 256 + threadIdx.x;   // V_TILES*64
    const int lane = g & 63;
    const int tile = g >> 6;
    int col = tile * 16 + (lane & 15);
    if (col >= V) col = V - 1;                         // pad clamp (masked later)
    const int k0 = (lane >> 4) * 8;
    const float* wp = W + (size_t)col * 32 + k0;
    float f[8];
    *reinterpret_cast<float4*>(f)     = *reinterpret_cast<const float4*>(wp);
    *reinterpret_cast<float4*>(f + 4) = *reinterpret_cast<const float4*>(wp + 4);
    Wf[g] = pack8h(f);
}

// emb[seq] -> fp16 B-operand fragments. Lane l: n = l&15, k = (l>>4)*8..+7.
__global__ __launch_bounds__(256) void prep_efrag(
    const int* __restrict__ seq, const float* __restrict__ emb,
    uint4* __restrict__ Ef)
{
    const int g    = blockIdx.x * 256 + threadIdx.x;   // NBLK*64
    const int lane = g & 63;
    const int c    = g >> 6;
    const int row  = c * 16 + (lane & 15);
    const int k0   = (lane >> 4) * 8;
    const int idx  = seq[row];
    const float* ep = emb + (size_t)idx * 32 + k0;
    float f[8];
    *reinterpret_cast<float4*>(f)     = *reinterpret_cast<const float4*>(ep);
    *reinterpret_cast<float4*>(f + 4) = *reinterpret_cast<const float4*>(ep + 4);
    Ef[g] = pack8h(f);
}

__global__ __launch_bounds__(TPB) void bigram_main(
    const uint4* __restrict__ Wf,
    const float* __restrict__ bias,
    const uint4* __restrict__ Ef,
    float*       __restrict__ logits,
    float*       __restrict__ rowsum,
    int V)
{
    __shared__ float buf[ROWS_PB][TSTR];     // 128.25 KB
    __shared__ float lsum[WAVES][ROWS_PB];   // 1 KB

    const int tid  = threadIdx.x;
    const int lane = tid & 63;
    const int wid  = tid >> 6;
    const int lgrp = lane >> 4;
    const int lcol = lane & 15;
    const int b    = blockIdx.x;

    // emb fragments for this block's 16 rows: loop-invariant.
    const f16x8 E = __builtin_bit_cast(f16x8, Ef[(size_t)b * 64 + lane]);
    const int wcol = wid * 128;                // wave's col offset inside window
    float rs = 0.f;

    // Preload window 0's W fragments.
    uint4 Wc[8];
#pragma unroll
    for (int t = 0; t < 8; ++t)
        Wc[t] = Wf[(size_t)(wid * 8 + t) * 64 + lane];

    for (int s = 0; s < NWIN; ++s) {
        const int  cbase = s * WIN;
        const bool last  = (s == NWIN - 1);

        // Prefetch next window's W fragments (independent of current compute;
        // completes during compute+store phases).
        const int sp = (s + 1 < NWIN) ? s + 1 : s;
        uint4 Wn[8];
#pragma unroll
        for (int t = 0; t < 8; ++t)
            Wn[t] = Wf[(size_t)(sp * (WIN / 16) + wid * 8 + t) * 64 + lane];

#pragma unroll
        for (int t = 0; t < 8; ++t) {
            const f32x4 z = {0.f, 0.f, 0.f, 0.f};
            f32x4 acc = __builtin_amdgcn_mfma_f32_16x16x32_f16(
                __builtin_bit_cast(f16x8, Wc[t]), E, z, 0, 0, 0);
            // D: seq row = lane&15; vocab col = cbase + wcol + t*16 + lgrp*4 + j.
            const int c0 = cbase + wcol + t * 16 + lgrp * 4;
            f32x4 x;
            if (!last) {
                const float4 b4 = *reinterpret_cast<const float4*>(bias + c0);
                x = acc + f32x4{b4.x, b4.y, b4.z, b4.w};
                rs += __expf(x[0]) + __expf(x[1]) + __expf(x[2]) + __expf(x[3]);
            } else {
#pragma unroll
                for (int j = 0; j < 4; ++j) {
                    const int c = c0 + j;
                    x[j] = acc[j] + bias[c < V ? c : V - 1];
                    if (c < V) rs += __expf(x[j]);
                }
            }
            *reinterpret_cast<f32x4*>(&buf[lcol][wcol + t * 16 + lgrp * 4]) = x;
        }
        __syncthreads();

        // Store phase: wave w stores row w's 8KB window as 8 back-to-back
        // 1KB nt dwordx4 bursts (full 128B lines -> clean write-combine,
        // no L2 allocate -> Wf stays L2-resident).
        {
            const int n = b * ROWS_PB + wid;
            float* dst = logits + (size_t)n * V + cbase;
#pragma unroll
            for (int i = 0; i < 8; ++i) {
                const int colL = i * 256 + lane * 4;
                const f32x4 v = *reinterpret_cast<const f32x4*>(&buf[wid][colL]);
                if (!last) {
                    __builtin_nontemporal_store(v, reinterpret_cast<f32x4*>(dst + colL));
                } else {
                    const int cg = cbase + colL;
                    if (cg + 3 < V) {
                        __builtin_nontemporal_store(v, reinterpret_cast<f32x4*>(dst + colL));
                    } else {
#pragma unroll
                        for (int j = 0; j < 4; ++j)
                            if (cg + j < V)
                                __builtin_nontemporal_store(v[j], dst + colL + j);
                    }
                }
            }
        }
        __syncthreads();   // protect buf before next window overwrites

#pragma unroll
        for (int t = 0; t < 8; ++t) Wc[t] = Wn[t];
    }

    // In-block rowsum: reduce over lgrp lanes, then over the 16 waves.
    rs += __shfl_xor(rs, 16, 64);
    rs += __shfl_xor(rs, 32, 64);
    if (lane < 16) lsum[wid][lane] = rs;
    __syncthreads();
    if (tid < ROWS_PB) {
        float t = 0.f;
#pragma unroll
        for (int w = 0; w < WAVES; ++w) t += lsum[w][tid];
        rowsum[b * ROWS_PB + tid] = t;
    }
}

// loss = mean( log(rowsum[n]) - (dot(emb[seq[n]], W[pred[n]]) + b[pred[n]]) )
__global__ void bigram_loss(
    const int*   __restrict__ seq,
    const int*   __restrict__ pred,
    const float* __restrict__ emb,
    const float* __restrict__ W,
    const float* __restrict__ bias,
    const float* __restrict__ rowsum,
    float*       __restrict__ loss,
    int N)
{
    const int tid = threadIdx.x;
    float local = 0.f;
    for (int n = blockIdx.x * blockDim.x + tid; n < N; n += gridDim.x * blockDim.x) {
        const int r = seq[n], t = pred[n];
        const float4* e4 = reinterpret_cast<const float4*>(emb + (size_t)r * 32);
        const float4* w4 = reinterpret_cast<const float4*>(W + (size_t)t * 32);
        float d = bias[t];
#pragma unroll
        for (int i = 0; i < 8; ++i) {
            const float4 e = e4[i], w = w4[i];
            d += e.x * w.x + e.y * w.y + e.z * w.z + e.w * w.w;
        }
        local += __logf(rowsum[n]) - d;
    }
#pragma unroll
    for (int off = 32; off >= 1; off >>= 1) local += __shfl_xor(local, off, 64);
    __shared__ float r4[4];
    if ((tid & 63) == 0) r4[tid >> 6] = local;
    __syncthreads();
    if (tid == 0) {
        const float s = r4[0] + r4[1] + r4[2] + r4[3];
        atomicAdd(loss, s / (float)N);
    }
}

extern "C" void kernel_launch(void* const* d_in, const int* in_sizes, int n_in,
                              void* d_out, int out_size, void* d_ws, size_t ws_size,
                              hipStream_t stream)
{
    const int*   seq  = (const int*)d_in[0];
    const int*   pred = (const int*)d_in[1];
    const float* emb  = (const float*)d_in[2];
    const float* W    = (const float*)d_in[3];
    const float* bias = (const float*)d_in[4];

    const int N = in_sizes[0];      // 4096
    const int V = in_sizes[4];      // 100277

    float* logits = (float*)d_out;
    float* loss   = logits + (size_t)N * V;

    char*  ws     = (char*)d_ws;
    float* rowsum = (float*)(ws + RS_OFF);
    uint4* Ef     = (uint4*)(ws + EF_OFF);
    uint4* Wf     = (uint4*)(ws + WF_OFF);

    hipMemsetAsync((void*)loss, 0, sizeof(float), stream);

    hipLaunchKernelGGL(prep_wfrag, dim3(V_TILES * 64 / 256), dim3(256), 0, stream,
                       W, Wf, V);
    hipLaunchKernelGGL(prep_efrag, dim3(NBLK * 64 / 256), dim3(256), 0, stream,
                       seq, emb, Ef);

    hipLaunchKernelGGL(bigram_main, dim3(NBLK), dim3(TPB), 0, stream,
                       Wf, bias, Ef, logits, rowsum, V);

    hipLaunchKernelGGL(bigram_loss, dim3(16), dim3(256), 0, stream,
                       seq, pred, emb, W, bias, rowsum, loss, N);
}